// Round 4
// baseline (238.918 us; speedup 1.0000x reference)
//
#include <hip/hip_runtime.h>

// Cascaded convex upsampling (SEAFLOW3DP): x16 -> x8 -> x4 -> x2 -> x1.
// One thread per PAIR of horizontally-adjacent coarse pixels. sy-major
// two-pass accumulation (#pragma unroll 1) keeps VGPR ~100 -> 4 waves/SIMD
// while retaining dwordx2 mask loads and dwordx4 stores.
// Stages 1-3 leave most CUs idle -> extra blocks prefetch the NEXT stages'
// masks into Infinity Cache (the harness's 453MB ws-poison evicts L3 right
// before launch), so stage 4 reads mask2 from L3 instead of HBM.
//
// Mask layout (N,36,Hc,Wc), channel c = k*4 + sy*2 + sx, k = kh*3 + kw.
// Zero-padded taps contribute 0 to the numerator but keep their softmax
// weight in the denominator -> zero the TAP value, not the weight.

#define NB 4  // batch

template <int Hc, int Wc>
__global__ __launch_bounds__(256, 4) void convex_up2(
    const float* __restrict__ flowIn,  // (NB,2,Hc,Wc)
    const float* __restrict__ dzIn,    // (NB,1,Hc,Wc)
    const float* __restrict__ mask,    // (NB,36,Hc,Wc)
    float* __restrict__ flowOut,       // ch0 at n*flowOutBS, ch1 at +H2*W2
    float* __restrict__ dzOut,         // at n*dzOutBS
    int flowOutBS, int dzOutBS,
    const float4* __restrict__ pfSrc, int pfCount,  // L3 prefetch range
    float* __restrict__ pfSink)
{
    constexpr int HW = Hc * Wc;
    constexpr int W2 = Wc * 2;
    constexpr int WP = Wc / 2;                 // coarse-pixel pairs per row
    constexpr int WORK = NB * Hc * WP / 256;   // work blocks (exact multiple)

    if (blockIdx.x >= WORK) {
        // ---- prefetch block: stream pfSrc through L3, loads kept alive by
        // a never-taken predicated write ----
        int tid = (blockIdx.x - WORK) * 256 + threadIdx.x;
        int stride = (gridDim.x - WORK) * 256;
        float s = 0.f;
        for (int i = tid; i < pfCount; i += stride) {
            float4 v = pfSrc[i];
            s += v.x + v.y + v.z + v.w;
        }
        if (s > 1e30f) pfSink[tid & 1023] = s;  // never true for mask data
        return;
    }

    int idx = blockIdx.x * 256 + threadIdx.x;
    int wp = idx % WP;
    int t  = idx / WP;
    int hc = t % Hc;
    int n  = t / Hc;
    int wc0 = 2 * wp;  // left coarse pixel (A); right is wc0+1 (B)

    // ---- tap loads: 3 rows x 4 cols (wc0-1 .. wc0+2) x 3 channels ----
    const float* fb = flowIn + (size_t)n * 2 * HW;
    const float* db = dzIn   + (size_t)n * HW;

    bool lv = (wp > 0);
    bool rv = (wp < WP - 1);
    int lc = lv ? wc0 - 1 : 0;        // clamped edge addresses (value zeroed)
    int rc = rv ? wc0 + 2 : Wc - 1;

    float tx[3][4], ty[3][4], tz[3][4];
#pragma unroll
    for (int kh = 0; kh < 3; ++kh) {
        int hh = hc + kh - 1;
        bool vh = (unsigned)hh < (unsigned)Hc;
        int hr = min(max(hh, 0), Hc - 1);
        const float* rx = fb + (size_t)hr * Wc;
        const float* ry = rx + HW;
        const float* rz = db + (size_t)hr * Wc;

        float2 cx = *(const float2*)(rx + wc0);
        float2 cy = *(const float2*)(ry + wc0);
        float2 cz = *(const float2*)(rz + wc0);
        float lx = rx[lc], ly = ry[lc], lz = rz[lc];
        float rxe = rx[rc], rye = ry[rc], rze = rz[rc];

        bool vl = vh && lv, vr = vh && rv;
        tx[kh][0] = vl ? lx : 0.f;   tx[kh][1] = vh ? cx.x : 0.f;
        tx[kh][2] = vh ? cx.y : 0.f; tx[kh][3] = vr ? rxe : 0.f;
        ty[kh][0] = vl ? ly : 0.f;   ty[kh][1] = vh ? cy.x : 0.f;
        ty[kh][2] = vh ? cy.y : 0.f; ty[kh][3] = vr ? rye : 0.f;
        tz[kh][0] = vl ? lz : 0.f;   tz[kh][1] = vh ? cz.x : 0.f;
        tz[kh][2] = vh ? cz.y : 0.f; tz[kh][3] = vr ? rze : 0.f;
    }

    const float* mb = mask + (size_t)n * 36 * HW + (size_t)hc * Wc + wc0;
    float* fo0 = flowOut + (size_t)n * flowOutBS;
    float* fo1 = fo0 + (size_t)(2 * Hc) * W2;
    float* dzo = dzOut + (size_t)n * dzOutBS;

    // ---- sy-major: two passes, each loads 18 mask dwordx2, 16 accumulators,
    // stores one fine row (3 x dwordx4). unroll 1 keeps VGPR pressure low. ----
#pragma unroll 1
    for (int sy = 0; sy < 2; ++sy) {
        float2 e[18];  // [k*2 + sx]; .x = pixel A, .y = pixel B
#pragma unroll
        for (int k = 0; k < 9; ++k) {
            e[k * 2 + 0] = *(const float2*)(mb + (size_t)(k * 4 + sy * 2 + 0) * HW);
            e[k * 2 + 1] = *(const float2*)(mb + (size_t)(k * 4 + sy * 2 + 1) * HW);
        }
#pragma unroll
        for (int i = 0; i < 18; ++i) {
            e[i].x = __expf(e[i].x);
            e[i].y = __expf(e[i].y);
        }

        // p: 0 = A/sx0, 1 = A/sx1, 2 = B/sx0, 3 = B/sx1  (= fine cols 4wp..4wp+3)
        float s[4] = {0, 0, 0, 0}, ax[4] = {0, 0, 0, 0},
              ay[4] = {0, 0, 0, 0}, az[4] = {0, 0, 0, 0};
#pragma unroll
        for (int k = 0; k < 9; ++k) {
            int kh = k / 3, kw = k % 3;
            float2 e0 = e[k * 2 + 0], e1 = e[k * 2 + 1];
            s[0] += e0.x; ax[0] += e0.x * tx[kh][kw];     ay[0] += e0.x * ty[kh][kw];     az[0] += e0.x * tz[kh][kw];
            s[1] += e1.x; ax[1] += e1.x * tx[kh][kw];     ay[1] += e1.x * ty[kh][kw];     az[1] += e1.x * tz[kh][kw];
            s[2] += e0.y; ax[2] += e0.y * tx[kh][kw + 1]; ay[2] += e0.y * ty[kh][kw + 1]; az[2] += e0.y * tz[kh][kw + 1];
            s[3] += e1.y; ax[3] += e1.y * tx[kh][kw + 1]; ay[3] += e1.y * ty[kh][kw + 1]; az[3] += e1.y * tz[kh][kw + 1];
        }

        float i0 = __builtin_amdgcn_rcpf(s[0]);
        float i1 = __builtin_amdgcn_rcpf(s[1]);
        float i2 = __builtin_amdgcn_rcpf(s[2]);
        float i3 = __builtin_amdgcn_rcpf(s[3]);
        size_t ro = (size_t)(2 * hc + sy) * W2 + 4 * wp;
        float4 vx = {2.f * ax[0] * i0, 2.f * ax[1] * i1, 2.f * ax[2] * i2, 2.f * ax[3] * i3};
        float4 vy = {2.f * ay[0] * i0, 2.f * ay[1] * i1, 2.f * ay[2] * i2, 2.f * ay[3] * i3};
        float4 vz = {az[0] * i0, az[1] * i1, az[2] * i2, az[3] * i3};
        *(float4*)(fo0 + ro) = vx;
        *(float4*)(fo1 + ro) = vy;
        *(float4*)(dzo + ro) = vz;
    }
}

extern "C" void kernel_launch(void* const* d_in, const int* in_sizes, int n_in,
                              void* d_out, int out_size, void* d_ws, size_t ws_size,
                              hipStream_t stream) {
    const float* flow16 = (const float*)d_in[0];  // (4,2,48,64)
    const float* dz16   = (const float*)d_in[1];  // (4,1,48,64)
    const float* mask16 = (const float*)d_in[2];  // (4,36,48,64)
    const float* mask8  = (const float*)d_in[3];  // (4,36,96,128)
    const float* mask4  = (const float*)d_in[4];  // (4,36,192,256)
    const float* mask2  = (const float*)d_in[5];  // (4,36,384,512)

    float* ws = (float*)d_ws;
    float* flowA = ws;                               // 4*2*96*128
    float* dzA   = flowA + 4 * 2 * 96 * 128;         // 4*1*96*128
    float* flowB = dzA   + 4 * 96 * 128;             // 4*2*192*256
    float* dzB   = flowB + 4 * 2 * 192 * 256;        // 4*1*192*256
    float* flowC = dzB   + 4 * 192 * 256;            // 4*2*384*512
    float* dzC   = flowC + 4 * 2 * 384 * 512;        // 4*1*384*512
    float* pfSink = ws + (16 << 20);                 // far past intermediates

    float* out = (float*)d_out;                      // (4,3,768,1024)
    const int HW1 = 768 * 1024;

    // mask2 as float4 stream for prefetch: 4*36*384*512/4 = 7,077,888 float4
    const float4* m2v = (const float4*)mask2;
    const int m2Half = 7077888 / 2;
    const float4* m4v = (const float4*)mask4;        // 1,769,472 float4

    // stage 1: 24 work blocks + 360 prefetch (mask4 -> L3)
    hipLaunchKernelGGL((convex_up2<48, 64>), dim3(24 + 360), dim3(256), 0, stream,
                       flow16, dz16, mask16, flowA, dzA, 2 * 96 * 128, 96 * 128,
                       m4v, 1769472, pfSink);
    // stage 2: 96 work blocks + 672 prefetch (mask2 first half -> L3)
    hipLaunchKernelGGL((convex_up2<96, 128>), dim3(96 + 672), dim3(256), 0, stream,
                       flowA, dzA, mask8, flowB, dzB, 2 * 192 * 256, 192 * 256,
                       m2v, m2Half, pfSink);
    // stage 3: 384 work blocks + 640 prefetch (mask2 second half -> L3)
    hipLaunchKernelGGL((convex_up2<192, 256>), dim3(384 + 640), dim3(256), 0, stream,
                       flowB, dzB, mask4, flowC, dzC, 2 * 384 * 512, 384 * 512,
                       m2v + m2Half, m2Half, pfSink);
    // stage 4: 1536 work blocks, no prefetch; writes straight into d_out
    hipLaunchKernelGGL((convex_up2<384, 512>), dim3(1536), dim3(256), 0, stream,
                       flowC, dzC, mask2, out, out + 2 * HW1, 3 * HW1, 3 * HW1,
                       m2v, 0, pfSink);
}

// Round 5
// 224.742 us; speedup vs baseline: 1.0631x; 1.0631x over previous
//
#include <hip/hip_runtime.h>

// Cascaded convex upsampling (SEAFLOW3DP): x16 -> x8 -> x4 -> x2 -> x1.
// R5: stages 1-3 fused into one tile-recompute megakernel (768 blocks, each
// owns a 32x32 flowC tile; flowA/flowB halo regions recomputed in LDS).
// Stage 4 (the big one, ~150MB traffic) stays a separate sy-major kernel.
//
// Mask layout (N,36,Hc,Wc), channel c = k*4 + sy*2 + sx, k = kh*3 + kw.
// Zero-padded taps contribute 0 to the numerator but keep their softmax
// weight in the denominator -> zero the TAP value, not the weight.
// Flow premul = 2 per stage (folded into normalization); dz premul = 1.

#define NB 4  // batch

// ---------------- fused stages 1-3: 48x64 inputs -> flowC/dzC 384x512 ----
__global__ __launch_bounds__(256, 4) void fused123(
    const float* __restrict__ flow16, const float* __restrict__ dz16,
    const float* __restrict__ mask16, const float* __restrict__ mask8,
    const float* __restrict__ mask4,
    float* __restrict__ flowC, float* __restrict__ dzC)
{
    constexpr int H0 = 48,  W0 = 64,  HW0 = H0 * W0;
    constexpr int H1 = 96,  W1 = 128, HW1 = H1 * W1;
    constexpr int H2 = 192, W2 = 256, HW2 = H2 * W2;
    constexpr int H3 = 384, W3 = 512, HW3 = H3 * W3;

    __shared__ float sA[3][12][12];  // flowA region rows A1h-2..A1h+9
    __shared__ float sB[3][18][18];  // flowB region rows A2h-1..A2h+16

    int bid = blockIdx.x;
    int n  = bid / 192;
    int tt = bid % 192;
    int TR = tt / 16, TC = tt % 16;     // 12x16 tiles of 32x32 over 384x512
    int A2h = TR * 16, A2w = TC * 16;   // coarse base at 192x256
    int A1h = A2h / 2, A1w = A2w / 2;   // coarse base at 96x128

    const float* f16 = flow16 + (size_t)n * 2 * HW0;
    const float* d16 = dz16   + (size_t)n * HW0;
    const float* m16 = mask16 + (size_t)n * 36 * HW0;
    const float* m8  = mask8  + (size_t)n * 36 * HW1;
    const float* m4  = mask4  + (size_t)n * 36 * HW2;

    int tid = threadIdx.x;

    // ---- phase 1: flowA 12x12 halo region (stage 1) ----
    if (tid < 144) {
        int i = tid / 12, j = tid % 12;
        int gh = A1h - 2 + i, gw = A1w - 2 + j;   // global 96x128 coords
        float ox = 0.f, oy = 0.f, oz = 0.f;
        if ((unsigned)gh < (unsigned)H1 && (unsigned)gw < (unsigned)W1) {
            int ch = gh >> 1, cw = gw >> 1;       // 48x64 coords
            int q = (gh & 1) * 2 + (gw & 1);
            const float* mb = m16 + (size_t)q * HW0 + ch * W0 + cw;
            float e[9];
#pragma unroll
            for (int k = 0; k < 9; ++k) e[k] = __expf(mb[(size_t)(k * 4) * HW0]);
            float s = 0.f, ax = 0.f, ay = 0.f, az = 0.f;
#pragma unroll
            for (int kh = 0; kh < 3; ++kh) {
                int hh = ch + kh - 1;
                bool vh = (unsigned)hh < (unsigned)H0;
                int hcl = min(max(hh, 0), H0 - 1);
#pragma unroll
                for (int kw = 0; kw < 3; ++kw) {
                    int ww = cw + kw - 1;
                    bool v = vh && ((unsigned)ww < (unsigned)W0);
                    int wcl = min(max(ww, 0), W0 - 1);
                    int o = hcl * W0 + wcl;
                    float w = e[kh * 3 + kw];
                    s += w;
                    float txv = v ? f16[o] : 0.f;
                    float tyv = v ? f16[HW0 + o] : 0.f;
                    float tzv = v ? d16[o] : 0.f;
                    ax += w * txv; ay += w * tyv; az += w * tzv;
                }
            }
            float inv = __builtin_amdgcn_rcpf(s);
            ox = 2.f * ax * inv; oy = 2.f * ay * inv; oz = az * inv;
        }
        sA[0][i][j] = ox; sA[1][i][j] = oy; sA[2][i][j] = oz;
    }
    __syncthreads();

    // ---- phase 2: flowB 18x18 halo region (stage 2) ----
    for (int p = tid; p < 324; p += 256) {
        int i = p / 18, j = p % 18;
        int gh = A2h - 1 + i, gw = A2w - 1 + j;   // global 192x256 coords
        float ox = 0.f, oy = 0.f, oz = 0.f;
        if ((unsigned)gh < (unsigned)H2 && (unsigned)gw < (unsigned)W2) {
            int ch = gh >> 1, cw = gw >> 1;       // 96x128 coords
            int q = (gh & 1) * 2 + (gw & 1);
            const float* mb = m8 + (size_t)q * HW1 + ch * W1 + cw;
            float e[9];
#pragma unroll
            for (int k = 0; k < 9; ++k) e[k] = __expf(mb[(size_t)(k * 4) * HW1]);
            // sA local index of tap (ch+kh-1): (ch+kh-1) - (A1h-2) = (ch-A1h)+kh+1
            int li = ch - A1h + 2, lj = cw - A1w + 2;
            float s = 0.f, ax = 0.f, ay = 0.f, az = 0.f;
#pragma unroll
            for (int kh = 0; kh < 3; ++kh)
#pragma unroll
                for (int kw = 0; kw < 3; ++kw) {
                    float w = e[kh * 3 + kw];
                    s += w;
                    ax += w * sA[0][li + kh - 1][lj + kw - 1];
                    ay += w * sA[1][li + kh - 1][lj + kw - 1];
                    az += w * sA[2][li + kh - 1][lj + kw - 1];
                }
            float inv = __builtin_amdgcn_rcpf(s);
            ox = 2.f * ax * inv; oy = 2.f * ay * inv; oz = az * inv;
        }
        sB[0][i][j] = ox; sB[1][i][j] = oy; sB[2][i][j] = oz;
    }
    __syncthreads();

    // ---- phase 3: flowC 32x32 tile, 4 horizontally-consecutive px/thread ----
    int ph = tid / 8;          // tile row 0..31
    int j4 = tid % 8;          // col group; fine cols 4*j4 .. 4*j4+3
    int sy = ph & 1;
    int crow = A2h + (ph >> 1);          // mask4/flowB coarse row (192x256)
    int ccol = A2w + 2 * j4;             // left coarse col of the pair

    const float* mb = m4 + (size_t)(sy * 2) * HW2 + crow * W2 + ccol;
    float2 e0[9], e1[9];  // sx=0 / sx=1 channels; .x=left coarse col, .y=right
#pragma unroll
    for (int k = 0; k < 9; ++k) {
        e0[k] = *(const float2*)(mb + (size_t)(k * 4) * HW2);
        e1[k] = *(const float2*)(mb + (size_t)(k * 4 + 1) * HW2);
    }
#pragma unroll
    for (int k = 0; k < 9; ++k) {
        e0[k].x = __expf(e0[k].x); e0[k].y = __expf(e0[k].y);
        e1[k].x = __expf(e1[k].x); e1[k].y = __expf(e1[k].y);
    }

    // p: 0=(left,sx0) 1=(left,sx1) 2=(right,sx0) 3=(right,sx1) = fine cols 0..3
    float s[4] = {0, 0, 0, 0}, ax[4] = {0, 0, 0, 0},
          ay[4] = {0, 0, 0, 0}, az[4] = {0, 0, 0, 0};
    int lr = ph >> 1;          // sB local row base: (crow-1)-(A2h-1)
    int lc = 2 * j4;           // sB local col base: (ccol-1)-(A2w-1)
#pragma unroll
    for (int k = 0; k < 9; ++k) {
        int kh = k / 3, kw = k % 3;
        float tl0 = sB[0][lr + kh][lc + kw],     tl1 = sB[1][lr + kh][lc + kw],
              tl2 = sB[2][lr + kh][lc + kw];
        float tr0 = sB[0][lr + kh][lc + kw + 1], tr1 = sB[1][lr + kh][lc + kw + 1],
              tr2 = sB[2][lr + kh][lc + kw + 1];
        float w0 = e0[k].x, w1 = e1[k].x, w2 = e0[k].y, w3 = e1[k].y;
        s[0] += w0; ax[0] += w0 * tl0; ay[0] += w0 * tl1; az[0] += w0 * tl2;
        s[1] += w1; ax[1] += w1 * tl0; ay[1] += w1 * tl1; az[1] += w1 * tl2;
        s[2] += w2; ax[2] += w2 * tr0; ay[2] += w2 * tr1; az[2] += w2 * tr2;
        s[3] += w3; ax[3] += w3 * tr0; ay[3] += w3 * tr1; az[3] += w3 * tr2;
    }
    float i0 = __builtin_amdgcn_rcpf(s[0]);
    float i1 = __builtin_amdgcn_rcpf(s[1]);
    float i2 = __builtin_amdgcn_rcpf(s[2]);
    float i3 = __builtin_amdgcn_rcpf(s[3]);

    size_t ro = (size_t)(TR * 32 + ph) * W3 + (TC * 32 + 4 * j4);
    float* fx = flowC + (size_t)n * 2 * HW3 + ro;
    float* fz = dzC   + (size_t)n * HW3 + ro;
    float4 vx = {2.f * ax[0] * i0, 2.f * ax[1] * i1, 2.f * ax[2] * i2, 2.f * ax[3] * i3};
    float4 vy = {2.f * ay[0] * i0, 2.f * ay[1] * i1, 2.f * ay[2] * i2, 2.f * ay[3] * i3};
    float4 vz = {az[0] * i0, az[1] * i1, az[2] * i2, az[3] * i3};
    *(float4*)(fx)       = vx;
    *(float4*)(fx + HW3) = vy;
    *(float4*)(fz)       = vz;
}

// ---------------- stage 4: sy-major pair kernel (R4 structure, no prefetch) --
template <int Hc, int Wc>
__global__ __launch_bounds__(256, 4) void convex_up2(
    const float* __restrict__ flowIn,  // (NB,2,Hc,Wc)
    const float* __restrict__ dzIn,    // (NB,1,Hc,Wc)
    const float* __restrict__ mask,    // (NB,36,Hc,Wc)
    float* __restrict__ flowOut,       // ch0 at n*flowOutBS, ch1 at +H2*W2
    float* __restrict__ dzOut,         // at n*dzOutBS
    int flowOutBS, int dzOutBS)
{
    constexpr int HW = Hc * Wc;
    constexpr int W2 = Wc * 2;
    constexpr int WP = Wc / 2;  // coarse-pixel pairs per row

    int idx = blockIdx.x * 256 + threadIdx.x;  // grid sized exactly
    int wp = idx % WP;
    int t  = idx / WP;
    int hc = t % Hc;
    int n  = t / Hc;
    int wc0 = 2 * wp;  // left coarse pixel (A); right is wc0+1 (B)

    const float* fb = flowIn + (size_t)n * 2 * HW;
    const float* db = dzIn   + (size_t)n * HW;

    bool lv = (wp > 0);
    bool rv = (wp < WP - 1);
    int lc = lv ? wc0 - 1 : 0;        // clamped edge addresses (value zeroed)
    int rc = rv ? wc0 + 2 : Wc - 1;

    float tx[3][4], ty[3][4], tz[3][4];
#pragma unroll
    for (int kh = 0; kh < 3; ++kh) {
        int hh = hc + kh - 1;
        bool vh = (unsigned)hh < (unsigned)Hc;
        int hr = min(max(hh, 0), Hc - 1);
        const float* rx = fb + (size_t)hr * Wc;
        const float* ry = rx + HW;
        const float* rz = db + (size_t)hr * Wc;

        float2 cx = *(const float2*)(rx + wc0);
        float2 cy = *(const float2*)(ry + wc0);
        float2 cz = *(const float2*)(rz + wc0);
        float lx = rx[lc], ly = ry[lc], lz = rz[lc];
        float rxe = rx[rc], rye = ry[rc], rze = rz[rc];

        bool vl = vh && lv, vr = vh && rv;
        tx[kh][0] = vl ? lx : 0.f;   tx[kh][1] = vh ? cx.x : 0.f;
        tx[kh][2] = vh ? cx.y : 0.f; tx[kh][3] = vr ? rxe : 0.f;
        ty[kh][0] = vl ? ly : 0.f;   ty[kh][1] = vh ? cy.x : 0.f;
        ty[kh][2] = vh ? cy.y : 0.f; ty[kh][3] = vr ? rye : 0.f;
        tz[kh][0] = vl ? lz : 0.f;   tz[kh][1] = vh ? cz.x : 0.f;
        tz[kh][2] = vh ? cz.y : 0.f; tz[kh][3] = vr ? rze : 0.f;
    }

    const float* mb = mask + (size_t)n * 36 * HW + (size_t)hc * Wc + wc0;
    float* fo0 = flowOut + (size_t)n * flowOutBS;
    float* fo1 = fo0 + (size_t)(2 * Hc) * W2;
    float* dzo = dzOut + (size_t)n * dzOutBS;

#pragma unroll 1
    for (int sy = 0; sy < 2; ++sy) {
        float2 e[18];  // [k*2 + sx]; .x = pixel A, .y = pixel B
#pragma unroll
        for (int k = 0; k < 9; ++k) {
            e[k * 2 + 0] = *(const float2*)(mb + (size_t)(k * 4 + sy * 2 + 0) * HW);
            e[k * 2 + 1] = *(const float2*)(mb + (size_t)(k * 4 + sy * 2 + 1) * HW);
        }
#pragma unroll
        for (int i = 0; i < 18; ++i) {
            e[i].x = __expf(e[i].x);
            e[i].y = __expf(e[i].y);
        }

        float s[4] = {0, 0, 0, 0}, ax[4] = {0, 0, 0, 0},
              ay[4] = {0, 0, 0, 0}, az[4] = {0, 0, 0, 0};
#pragma unroll
        for (int k = 0; k < 9; ++k) {
            int kh = k / 3, kw = k % 3;
            float2 e0 = e[k * 2 + 0], e1 = e[k * 2 + 1];
            s[0] += e0.x; ax[0] += e0.x * tx[kh][kw];     ay[0] += e0.x * ty[kh][kw];     az[0] += e0.x * tz[kh][kw];
            s[1] += e1.x; ax[1] += e1.x * tx[kh][kw];     ay[1] += e1.x * ty[kh][kw];     az[1] += e1.x * tz[kh][kw];
            s[2] += e0.y; ax[2] += e0.y * tx[kh][kw + 1]; ay[2] += e0.y * ty[kh][kw + 1]; az[2] += e0.y * tz[kh][kw + 1];
            s[3] += e1.y; ax[3] += e1.y * tx[kh][kw + 1]; ay[3] += e1.y * ty[kh][kw + 1]; az[3] += e1.y * tz[kh][kw + 1];
        }

        float i0 = __builtin_amdgcn_rcpf(s[0]);
        float i1 = __builtin_amdgcn_rcpf(s[1]);
        float i2 = __builtin_amdgcn_rcpf(s[2]);
        float i3 = __builtin_amdgcn_rcpf(s[3]);
        size_t ro = (size_t)(2 * hc + sy) * W2 + 4 * wp;
        float4 vx = {2.f * ax[0] * i0, 2.f * ax[1] * i1, 2.f * ax[2] * i2, 2.f * ax[3] * i3};
        float4 vy = {2.f * ay[0] * i0, 2.f * ay[1] * i1, 2.f * ay[2] * i2, 2.f * ay[3] * i3};
        float4 vz = {az[0] * i0, az[1] * i1, az[2] * i2, az[3] * i3};
        *(float4*)(fo0 + ro) = vx;
        *(float4*)(fo1 + ro) = vy;
        *(float4*)(dzo + ro) = vz;
    }
}

extern "C" void kernel_launch(void* const* d_in, const int* in_sizes, int n_in,
                              void* d_out, int out_size, void* d_ws, size_t ws_size,
                              hipStream_t stream) {
    const float* flow16 = (const float*)d_in[0];  // (4,2,48,64)
    const float* dz16   = (const float*)d_in[1];  // (4,1,48,64)
    const float* mask16 = (const float*)d_in[2];  // (4,36,48,64)
    const float* mask8  = (const float*)d_in[3];  // (4,36,96,128)
    const float* mask4  = (const float*)d_in[4];  // (4,36,192,256)
    const float* mask2  = (const float*)d_in[5];  // (4,36,384,512)

    float* ws = (float*)d_ws;
    float* flowC = ws;                             // 4*2*384*512
    float* dzC   = flowC + 4 * 2 * 384 * 512;      // 4*1*384*512

    float* out = (float*)d_out;                    // (4,3,768,1024)
    const int HW1 = 768 * 1024;

    // fused stages 1-3: 768 blocks (4 batches x 192 tiles of 32x32)
    hipLaunchKernelGGL(fused123, dim3(NB * 192), dim3(256), 0, stream,
                       flow16, dz16, mask16, mask8, mask4, flowC, dzC);
    // stage 4: 384x512 -> 768x1024 straight into d_out (flow ch0,1; dz ch2)
    hipLaunchKernelGGL((convex_up2<384, 512>), dim3(NB * 384 * 256 / 256), dim3(256), 0, stream,
                       flowC, dzC, mask2, out, out + 2 * HW1, 3 * HW1, 3 * HW1);
}

// Round 6
// 223.579 us; speedup vs baseline: 1.0686x; 1.0052x over previous
//
#include <hip/hip_runtime.h>

// SEAFLOW3DP cascaded convex upsampling, FULLY FUSED: one kernel, 768 blocks.
// Each block owns a 64x64 output tile (= 32x32 flowC tile) and recomputes the
// whole cascade in LDS:
//   phase 1: flowA  12x12 halo region (stage 1, from flow16/dz16/mask16)
//   phase 2: flowB  20x20 halo region (stage 2, taps from sA)
//   phase 3: flowC  34x34 halo region (stage 3, taps from sB)
//   phase 4: 64x64 output tile        (stage 4, taps from sC, mask2 streamed)
// Out-of-grid halo cells are stored as 0 in LDS, which exactly reproduces the
// zero-padding semantics (tap contributes 0, softmax weight stays in denom).
// Flow premul = 2 per stage (folded into normalization); dz premul = 1.
// LDS rows padded to odd strides -> <=2-way bank aliasing (free on CDNA4).

#define NB 4  // batch

__global__ __launch_bounds__(256, 4) void seaflow_fused(
    const float* __restrict__ flow16, const float* __restrict__ dz16,
    const float* __restrict__ mask16, const float* __restrict__ mask8,
    const float* __restrict__ mask4,  const float* __restrict__ mask2,
    float* __restrict__ out)  // (NB,3,768,1024): flow ch0,1; dz ch2
{
    constexpr int H0 = 48,  W0 = 64,   HW0 = H0 * W0;
    constexpr int H1 = 96,  W1 = 128,  HW1 = H1 * W1;
    constexpr int H2 = 192, W2 = 256,  HW2 = H2 * W2;
    constexpr int H3 = 384, W3 = 512,  HW3 = H3 * W3;
    constexpr int W4 = 1024, HW4 = 768 * 1024;

    __shared__ float sA[3][12][13];  // flowA, base (A1h-2, A1w-2)
    __shared__ float sB[3][20][21];  // flowB, base (A2h-2, A2w-2)
    __shared__ float sC[3][34][35];  // flowC, base (A3h-1, A3w-1)

    int bid = blockIdx.x;
    int n  = bid / 192;
    int tt = bid % 192;
    int TR = tt / 16, TC = tt % 16;   // 12x16 tiles of 32x32 over flowC
    int A3h = TR * 32, A3w = TC * 32;
    int A2h = TR * 16, A2w = TC * 16;
    int A1h = TR * 8,  A1w = TC * 8;

    const float* f16 = flow16 + (size_t)n * 2 * HW0;
    const float* d16 = dz16   + (size_t)n * HW0;
    const float* m16 = mask16 + (size_t)n * 36 * HW0;
    const float* m8  = mask8  + (size_t)n * 36 * HW1;
    const float* m4  = mask4  + (size_t)n * 36 * HW2;
    const float* m2  = mask2  + (size_t)n * 36 * HW3;

    int tid = threadIdx.x;

    // ---- phase 1: flowA 12x12 region (stage 1; taps from global, clamped
    // addresses with zeroed values at the grid border) ----
    if (tid < 144) {
        int i = tid / 12, j = tid % 12;
        int gh = A1h - 2 + i, gw = A1w - 2 + j;   // 96x128 coords
        float ox = 0.f, oy = 0.f, oz = 0.f;
        if ((unsigned)gh < (unsigned)H1 && (unsigned)gw < (unsigned)W1) {
            int ch = gh >> 1, cw = gw >> 1;       // 48x64 coords
            int q = (gh & 1) * 2 + (gw & 1);
            const float* mb = m16 + (size_t)q * HW0 + ch * W0 + cw;
            float e[9];
#pragma unroll
            for (int k = 0; k < 9; ++k) e[k] = __expf(mb[(size_t)(k * 4) * HW0]);
            float s = 0.f, ax = 0.f, ay = 0.f, az = 0.f;
#pragma unroll
            for (int kh = 0; kh < 3; ++kh) {
                int hh = ch + kh - 1;
                bool vh = (unsigned)hh < (unsigned)H0;
                int hcl = min(max(hh, 0), H0 - 1);
#pragma unroll
                for (int kw = 0; kw < 3; ++kw) {
                    int ww = cw + kw - 1;
                    bool v = vh && ((unsigned)ww < (unsigned)W0);
                    int wcl = min(max(ww, 0), W0 - 1);
                    int o = hcl * W0 + wcl;
                    float w = e[kh * 3 + kw];
                    s += w;
                    ax += w * (v ? f16[o] : 0.f);
                    ay += w * (v ? f16[HW0 + o] : 0.f);
                    az += w * (v ? d16[o] : 0.f);
                }
            }
            float inv = __builtin_amdgcn_rcpf(s);
            ox = 2.f * ax * inv; oy = 2.f * ay * inv; oz = az * inv;
        }
        sA[0][i][j] = ox; sA[1][i][j] = oy; sA[2][i][j] = oz;
    }
    __syncthreads();

    // ---- phase 2: flowB 20x20 region (stage 2; taps from sA) ----
    for (int p = tid; p < 400; p += 256) {
        int i = p / 20, j = p % 20;
        int gh = A2h - 2 + i, gw = A2w - 2 + j;   // 192x256 coords
        float ox = 0.f, oy = 0.f, oz = 0.f;
        if ((unsigned)gh < (unsigned)H2 && (unsigned)gw < (unsigned)W2) {
            int ch = gh >> 1, cw = gw >> 1;       // 96x128 coords
            int q = (gh & 1) * 2 + (gw & 1);
            const float* mb = m8 + (size_t)q * HW1 + ch * W1 + cw;
            float e[9];
#pragma unroll
            for (int k = 0; k < 9; ++k) e[k] = __expf(mb[(size_t)(k * 4) * HW1]);
            int li = ch - A1h + 2, lj = cw - A1w + 2;  // sA local center
            float s = 0.f, ax = 0.f, ay = 0.f, az = 0.f;
#pragma unroll
            for (int kh = 0; kh < 3; ++kh)
#pragma unroll
                for (int kw = 0; kw < 3; ++kw) {
                    float w = e[kh * 3 + kw];
                    s += w;
                    ax += w * sA[0][li + kh - 1][lj + kw - 1];
                    ay += w * sA[1][li + kh - 1][lj + kw - 1];
                    az += w * sA[2][li + kh - 1][lj + kw - 1];
                }
            float inv = __builtin_amdgcn_rcpf(s);
            ox = 2.f * ax * inv; oy = 2.f * ay * inv; oz = az * inv;
        }
        sB[0][i][j] = ox; sB[1][i][j] = oy; sB[2][i][j] = oz;
    }
    __syncthreads();

    // ---- phase 3: flowC 34x34 region (stage 3; taps from sB) ----
    for (int p = tid; p < 1156; p += 256) {
        int i = p / 34, j = p % 34;
        int gh = A3h - 1 + i, gw = A3w - 1 + j;   // 384x512 coords
        float ox = 0.f, oy = 0.f, oz = 0.f;
        if ((unsigned)gh < (unsigned)H3 && (unsigned)gw < (unsigned)W3) {
            int ch = gh >> 1, cw = gw >> 1;       // 192x256 coords
            int q = (gh & 1) * 2 + (gw & 1);
            const float* mb = m4 + (size_t)q * HW2 + ch * W2 + cw;
            float e[9];
#pragma unroll
            for (int k = 0; k < 9; ++k) e[k] = __expf(mb[(size_t)(k * 4) * HW2]);
            int li = ch - A2h + 2, lj = cw - A2w + 2;  // sB local center
            float s = 0.f, ax = 0.f, ay = 0.f, az = 0.f;
#pragma unroll
            for (int kh = 0; kh < 3; ++kh)
#pragma unroll
                for (int kw = 0; kw < 3; ++kw) {
                    float w = e[kh * 3 + kw];
                    s += w;
                    ax += w * sB[0][li + kh - 1][lj + kw - 1];
                    ay += w * sB[1][li + kh - 1][lj + kw - 1];
                    az += w * sB[2][li + kh - 1][lj + kw - 1];
                }
            float inv = __builtin_amdgcn_rcpf(s);
            ox = 2.f * ax * inv; oy = 2.f * ay * inv; oz = az * inv;
        }
        sC[0][i][j] = ox; sC[1][i][j] = oy; sC[2][i][j] = oz;
    }
    __syncthreads();

    // ---- phase 4: 64x64 output tile (stage 4; taps from sC, mask2 HBM) ----
    // Thread -> coarse (row pr(+16), col pair cp); 2 pairs/thread, sy-major.
    int pr = tid >> 4;       // 0..15
    int cp = tid & 15;       // col pair 0..15 (coarse cols 2cp, 2cp+1)
#pragma unroll 1
    for (int it = 0; it < 2; ++it) {
        int r = pr + 16 * it;                 // coarse row in tile, 0..31
        // taps from sC: rows r..r+2 (local base r), cols 2cp..2cp+3
        float t[3][3][4];
#pragma unroll
        for (int c = 0; c < 3; ++c)
#pragma unroll
            for (int kh = 0; kh < 3; ++kh)
#pragma unroll
                for (int w = 0; w < 4; ++w)
                    t[c][kh][w] = sC[c][r + kh][2 * cp + w];

        const float* mb = m2 + (size_t)(A3h + r) * W3 + (A3w + 2 * cp);
        float* ob = out + (size_t)n * 3 * HW4
                        + (size_t)(2 * (A3h + r)) * W4 + (2 * A3w + 4 * cp);

#pragma unroll 1
        for (int sy = 0; sy < 2; ++sy) {
            float2 e[18];  // [k*2 + sx]; .x = left coarse px, .y = right
#pragma unroll
            for (int k = 0; k < 9; ++k) {
                e[k * 2 + 0] = *(const float2*)(mb + (size_t)(k * 4 + sy * 2 + 0) * HW3);
                e[k * 2 + 1] = *(const float2*)(mb + (size_t)(k * 4 + sy * 2 + 1) * HW3);
            }
#pragma unroll
            for (int i = 0; i < 18; ++i) {
                e[i].x = __expf(e[i].x);
                e[i].y = __expf(e[i].y);
            }
            // p: 0=(L,sx0) 1=(L,sx1) 2=(R,sx0) 3=(R,sx1) = fine cols 4cp..4cp+3
            float s[4] = {0, 0, 0, 0}, ax[4] = {0, 0, 0, 0},
                  ay[4] = {0, 0, 0, 0}, az[4] = {0, 0, 0, 0};
#pragma unroll
            for (int k = 0; k < 9; ++k) {
                int kh = k / 3, kw = k % 3;
                float2 e0 = e[k * 2 + 0], e1 = e[k * 2 + 1];
                float tl0 = t[0][kh][kw],     tl1 = t[1][kh][kw],     tl2 = t[2][kh][kw];
                float tr0 = t[0][kh][kw + 1], tr1 = t[1][kh][kw + 1], tr2 = t[2][kh][kw + 1];
                s[0] += e0.x; ax[0] += e0.x * tl0; ay[0] += e0.x * tl1; az[0] += e0.x * tl2;
                s[1] += e1.x; ax[1] += e1.x * tl0; ay[1] += e1.x * tl1; az[1] += e1.x * tl2;
                s[2] += e0.y; ax[2] += e0.y * tr0; ay[2] += e0.y * tr1; az[2] += e0.y * tr2;
                s[3] += e1.y; ax[3] += e1.y * tr0; ay[3] += e1.y * tr1; az[3] += e1.y * tr2;
            }
            float i0 = __builtin_amdgcn_rcpf(s[0]);
            float i1 = __builtin_amdgcn_rcpf(s[1]);
            float i2 = __builtin_amdgcn_rcpf(s[2]);
            float i3 = __builtin_amdgcn_rcpf(s[3]);
            float* o = ob + (size_t)sy * W4;
            float4 vx = {2.f * ax[0] * i0, 2.f * ax[1] * i1, 2.f * ax[2] * i2, 2.f * ax[3] * i3};
            float4 vy = {2.f * ay[0] * i0, 2.f * ay[1] * i1, 2.f * ay[2] * i2, 2.f * ay[3] * i3};
            float4 vz = {az[0] * i0, az[1] * i1, az[2] * i2, az[3] * i3};
            *(float4*)(o)           = vx;
            *(float4*)(o + HW4)     = vy;
            *(float4*)(o + 2 * HW4) = vz;
        }
    }
}

extern "C" void kernel_launch(void* const* d_in, const int* in_sizes, int n_in,
                              void* d_out, int out_size, void* d_ws, size_t ws_size,
                              hipStream_t stream) {
    const float* flow16 = (const float*)d_in[0];  // (4,2,48,64)
    const float* dz16   = (const float*)d_in[1];  // (4,1,48,64)
    const float* mask16 = (const float*)d_in[2];  // (4,36,48,64)
    const float* mask8  = (const float*)d_in[3];  // (4,36,96,128)
    const float* mask4  = (const float*)d_in[4];  // (4,36,192,256)
    const float* mask2  = (const float*)d_in[5];  // (4,36,384,512)
    float* out = (float*)d_out;                   // (4,3,768,1024)

    // 768 blocks = 4 batches x (12x16) tiles of 64x64 output pixels
    hipLaunchKernelGGL(seaflow_fused, dim3(NB * 192), dim3(256), 0, stream,
                       flow16, dz16, mask16, mask8, mask4, mask2, out);
}